// Round 9
// baseline (988.515 us; speedup 1.0000x reference)
//
#include <hip/hip_runtime.h>
#include <hip/hip_fp16.h>

// GCN 3-layer, bucket-push layers, NO CSR (R22).
// Build: initcur -> scatter1 (R21: in-LDS counting sort into 489 fine
// buckets of 1024 nodes, atomic chunk reservation, pk1[fb*CAP_F..]) ->
// builddeg (slim: one pk1 read -> LDS degrees -> dinv + z1 half2).
// Layers (R22): block per fine bucket; acc[1024 x F] fp32 in LDS; stream
// own bucket's pk1 coalesced (16/8-deep), gather z[src] (divergent-line
// wall, same as pull: ~8.1us/M; R17 residency + R18 L1-bypass null),
// ds_add_f32 into acc, barrier, per-node epilogue from LDS. Deletes csr,
// rowptr, buildfine pass B (node sort) and the per-layer csr/rowptr
// streams. 2 blocks/CU = 32 waves (pull was 62% occupancy).
// R19/R20 push-at-wrong-granularity failed (barrier-serialized window
// cells); this push has no staging and no inner barriers.
// R13: z2 4xfp16 (8B/node). R14: z1/z3 half2 (4B/node).
// Math per layer (input u): z = u*dinv; s_i = sum_{e:dst=i} z[src_e];
//   out_i = (dinv_i*(s_i + z_i)) @ W + b   (self-loop folds into s+z).
// pk1 = (dst&1023) | (src<<10)  (29 bits, N < 2^19).

#define TPB 256
#define T_TILE 16384
#define FBB 10           // fine bucket = 1024 nodes
#define FB_MAX 512
#define CAP_F 34048      // per-bucket pk1 capacity: mean 32.7K, +7 sigma

// ---- init: bucket reservation cursors ----
__global__ void initcur(int* __restrict__ cur, int FB) {
    int t = threadIdx.x;
    if (t < FB) cur[t] = t * CAP_F;
}

// ---- pass 1: in-LDS counting-sort scatter into fine buckets (R21) ----
__global__ void __launch_bounds__(512)
scatter1(const int* __restrict__ dst, const int* __restrict__ src,
         int* __restrict__ cur, unsigned* __restrict__ pk1, int E, int FB) {
    __shared__ unsigned lpk[T_TILE];   // 64KB staged packed values
    __shared__ int lhist[FB_MAX];
    __shared__ int lexcl[FB_MAX];
    __shared__ int lcur[FB_MAX];
    __shared__ int lbase[FB_MAX];
    int blk = blockIdx.x, tid = threadIdx.x;
    lhist[tid] = 0;
    __syncthreads();
    int base = blk * T_TILE;
    // pass A: tile histogram over fine buckets (dst slice L2-hot for pass B)
    #pragma unroll 8
    for (int it = 0; it < T_TILE / 512; ++it) {
        int e = base + it * 512 + tid;
        if (e < E) atomicAdd(&lhist[((unsigned)dst[e]) >> FBB], 1);
    }
    __syncthreads();
    // exclusive scan over 512 bucket counts (FB=489 used)
    int hv = lhist[tid];
    lexcl[tid] = hv;
    __syncthreads();
    for (int off = 1; off < FB_MAX; off <<= 1) {
        int a = (tid >= off) ? lexcl[tid - off] : 0;
        __syncthreads();
        lexcl[tid] += a;
        __syncthreads();
    }
    lexcl[tid] -= hv;
    lcur[tid] = lexcl[tid];
    // reserve global chunk per bucket (one atomic per non-empty bucket)
    if (tid < FB && hv > 0) lbase[tid] = atomicAdd(&cur[tid], hv);
    __syncthreads();
    // pass B: place packed values into LDS at sorted positions
    #pragma unroll 8
    for (int it = 0; it < T_TILE / 512; ++it) {
        int e = base + it * 512 + tid;
        if (e < E) {
            unsigned d = (unsigned)dst[e];
            unsigned s = (unsigned)src[e];
            int pos = atomicAdd(&lcur[d >> FBB], 1);
            lpk[pos] = (d & 1023u) | (s << FBB);
        }
    }
    __syncthreads();
    // flush: wave-parallel per-bucket contiguous copy
    int w = tid >> 6, lane = tid & 63;
    for (int fb = w; fb < FB; fb += 8) {
        int cntb = lhist[fb];
        if (cntb == 0) continue;
        int lo = lexcl[fb], gb = lbase[fb];
        for (int t2 = lane; t2 < cntb; t2 += 64)
            pk1[gb + t2] = lpk[lo + t2];
    }
}

// ---- pass 2 (slim): per-bucket degrees -> dinv + z1 (half2) ----
__global__ void __launch_bounds__(1024)
builddeg(const unsigned* __restrict__ pk1, const int* __restrict__ cur,
         const float* __restrict__ x, float* __restrict__ dinv,
         unsigned* __restrict__ z1h, int N) {
    __shared__ int deg[1024];
    int fb = blockIdx.x, tid = threadIdx.x;
    deg[tid] = 0;
    __syncthreads();
    size_t pbase = (size_t)fb * CAP_F;
    int n = cur[fb] - (int)(fb * CAP_F);
    int k0 = 0;
    for (; k0 + 8192 <= n; k0 += 8192) {
        unsigned p[8];
        #pragma unroll
        for (int u = 0; u < 8; ++u)
            p[u] = __builtin_nontemporal_load(&pk1[pbase + k0 + tid + u * 1024]);
        #pragma unroll
        for (int u = 0; u < 8; ++u) atomicAdd(&deg[p[u] & 1023u], 1);
    }
    for (int k = k0 + tid; k < n; k += 1024)
        atomicAdd(&deg[__builtin_nontemporal_load(&pk1[pbase + k]) & 1023u], 1);
    __syncthreads();
    int i = (fb << FBB) + tid;
    if (i < N) {
        float di = rsqrtf((float)deg[tid] + 1.0f);
        dinv[i] = di;
        float2 xv = ((const float2*)x)[i];
        __half2 hz = __floats2half2_rn(xv.x * di, xv.y * di);
        z1h[i] = *(unsigned*)&hz;
    }
}

// ---------------- bucket-push GCN layers ----------------

__global__ void __launch_bounds__(1024)
glayer1(const unsigned* __restrict__ pk1, const int* __restrict__ cur,
        const unsigned* __restrict__ z1h, const float* __restrict__ dinv,
        const float* __restrict__ W1, const float* __restrict__ b1,
        uint2* __restrict__ z2h, int N) {
    __shared__ float acc[2048];
    int fb = blockIdx.x, tid = threadIdx.x;
    acc[tid] = 0.f; acc[tid + 1024] = 0.f;
    __syncthreads();
    size_t pbase = (size_t)fb * CAP_F;
    int n = cur[fb] - (int)(fb * CAP_F);
    int k0 = 0;
    for (; k0 + 16384 <= n; k0 += 16384) {
        unsigned p[16];
        #pragma unroll
        for (int u = 0; u < 16; ++u)
            p[u] = __builtin_nontemporal_load(&pk1[pbase + k0 + tid + u * 1024]);
        unsigned raw[16];
        #pragma unroll
        for (int u = 0; u < 16; ++u) raw[u] = z1h[p[u] >> FBB];
        #pragma unroll
        for (int u = 0; u < 16; ++u) {
            float2 v = __half22float2(*(__half2*)&raw[u]);
            unsigned d = (p[u] & 1023u) << 1;
            atomicAdd(&acc[d], v.x);
            atomicAdd(&acc[d + 1], v.y);
        }
    }
    for (; k0 + 4096 <= n; k0 += 4096) {
        unsigned p[4];
        #pragma unroll
        for (int u = 0; u < 4; ++u)
            p[u] = __builtin_nontemporal_load(&pk1[pbase + k0 + tid + u * 1024]);
        unsigned raw[4];
        #pragma unroll
        for (int u = 0; u < 4; ++u) raw[u] = z1h[p[u] >> FBB];
        #pragma unroll
        for (int u = 0; u < 4; ++u) {
            float2 v = __half22float2(*(__half2*)&raw[u]);
            unsigned d = (p[u] & 1023u) << 1;
            atomicAdd(&acc[d], v.x);
            atomicAdd(&acc[d + 1], v.y);
        }
    }
    for (int k = k0 + tid; k < n; k += 1024) {
        unsigned p = __builtin_nontemporal_load(&pk1[pbase + k]);
        unsigned zr = z1h[p >> FBB];
        float2 v = __half22float2(*(__half2*)&zr);
        unsigned d = (p & 1023u) << 1;
        atomicAdd(&acc[d], v.x);
        atomicAdd(&acc[d + 1], v.y);
    }
    __syncthreads();
    int i = (fb << FBB) + tid;
    if (i < N) {
        unsigned zr = z1h[i];
        float2 zi = __half22float2(*(__half2*)&zr);
        float di = dinv[i];
        float g0 = di * (acc[tid * 2] + zi.x);
        float g1 = di * (acc[tid * 2 + 1] + zi.y);
        float o0 = di * tanhf(fmaf(g0, W1[0], fmaf(g1, W1[4], b1[0])));
        float o1 = di * tanhf(fmaf(g0, W1[1], fmaf(g1, W1[5], b1[1])));
        float o2 = di * tanhf(fmaf(g0, W1[2], fmaf(g1, W1[6], b1[2])));
        float o3 = di * tanhf(fmaf(g0, W1[3], fmaf(g1, W1[7], b1[3])));
        __half2 ha = __floats2half2_rn(o0, o1);
        __half2 hb = __floats2half2_rn(o2, o3);
        uint2 packed;
        packed.x = *(unsigned*)&ha;
        packed.y = *(unsigned*)&hb;
        z2h[i] = packed;
    }
}

__global__ void __launch_bounds__(1024)
glayer2(const unsigned* __restrict__ pk1, const int* __restrict__ cur,
        const unsigned long long* __restrict__ z2h, const float* __restrict__ dinv,
        const float* __restrict__ W2, const float* __restrict__ b2,
        const float* __restrict__ W3, unsigned* __restrict__ z3h, int N) {
    __shared__ float acc[4096];  // 16KB
    int fb = blockIdx.x, tid = threadIdx.x;
    #pragma unroll
    for (int u = 0; u < 4; ++u) acc[tid + u * 1024] = 0.f;
    __syncthreads();
    size_t pbase = (size_t)fb * CAP_F;
    int n = cur[fb] - (int)(fb * CAP_F);
    int k0 = 0;
    for (; k0 + 8192 <= n; k0 += 8192) {
        unsigned p[8];
        #pragma unroll
        for (int u = 0; u < 8; ++u)
            p[u] = __builtin_nontemporal_load(&pk1[pbase + k0 + tid + u * 1024]);
        unsigned long long raw[8];
        #pragma unroll
        for (int u = 0; u < 8; ++u) raw[u] = z2h[p[u] >> FBB];
        #pragma unroll
        for (int u = 0; u < 8; ++u) {
            unsigned lo = (unsigned)raw[u], hi = (unsigned)(raw[u] >> 32);
            float2 f01 = __half22float2(*(__half2*)&lo);
            float2 f23 = __half22float2(*(__half2*)&hi);
            unsigned d = (p[u] & 1023u) << 2;
            atomicAdd(&acc[d], f01.x);
            atomicAdd(&acc[d + 1], f01.y);
            atomicAdd(&acc[d + 2], f23.x);
            atomicAdd(&acc[d + 3], f23.y);
        }
    }
    for (; k0 + 4096 <= n; k0 += 4096) {
        unsigned p[4];
        #pragma unroll
        for (int u = 0; u < 4; ++u)
            p[u] = __builtin_nontemporal_load(&pk1[pbase + k0 + tid + u * 1024]);
        unsigned long long raw[4];
        #pragma unroll
        for (int u = 0; u < 4; ++u) raw[u] = z2h[p[u] >> FBB];
        #pragma unroll
        for (int u = 0; u < 4; ++u) {
            unsigned lo = (unsigned)raw[u], hi = (unsigned)(raw[u] >> 32);
            float2 f01 = __half22float2(*(__half2*)&lo);
            float2 f23 = __half22float2(*(__half2*)&hi);
            unsigned d = (p[u] & 1023u) << 2;
            atomicAdd(&acc[d], f01.x);
            atomicAdd(&acc[d + 1], f01.y);
            atomicAdd(&acc[d + 2], f23.x);
            atomicAdd(&acc[d + 3], f23.y);
        }
    }
    for (int k = k0 + tid; k < n; k += 1024) {
        unsigned p = __builtin_nontemporal_load(&pk1[pbase + k]);
        unsigned long long zr = z2h[p >> FBB];
        unsigned lo = (unsigned)zr, hi = (unsigned)(zr >> 32);
        float2 f01 = __half22float2(*(__half2*)&lo);
        float2 f23 = __half22float2(*(__half2*)&hi);
        unsigned d = (p & 1023u) << 2;
        atomicAdd(&acc[d], f01.x);
        atomicAdd(&acc[d + 1], f01.y);
        atomicAdd(&acc[d + 2], f23.x);
        atomicAdd(&acc[d + 3], f23.y);
    }
    __syncthreads();
    int i = (fb << FBB) + tid;
    if (i < N) {
        unsigned long long zr = z2h[i];
        unsigned lo = (unsigned)zr, hi = (unsigned)(zr >> 32);
        float2 f01 = __half22float2(*(__half2*)&lo);
        float2 f23 = __half22float2(*(__half2*)&hi);
        float di = dinv[i];
        float g0 = di * (acc[tid * 4] + f01.x);
        float g1 = di * (acc[tid * 4 + 1] + f01.y);
        float g2 = di * (acc[tid * 4 + 2] + f23.x);
        float g3 = di * (acc[tid * 4 + 3] + f23.y);
        float h[4];
        #pragma unroll
        for (int c = 0; c < 4; ++c)
            h[c] = tanhf(b2[c] + g0 * W2[c] + g1 * W2[4 + c] + g2 * W2[8 + c] + g3 * W2[12 + c]);
        float v0 = h[0] * W3[0] + h[1] * W3[2] + h[2] * W3[4] + h[3] * W3[6];
        float v1 = h[0] * W3[1] + h[1] * W3[3] + h[2] * W3[5] + h[3] * W3[7];
        __half2 hz = __floats2half2_rn(v0 * di, v1 * di);
        z3h[i] = *(unsigned*)&hz;
    }
}

__global__ void __launch_bounds__(1024)
glayer3(const unsigned* __restrict__ pk1, const int* __restrict__ cur,
        const unsigned* __restrict__ z3h, const float* __restrict__ dinv,
        const float* __restrict__ b3, float* __restrict__ out, int N) {
    __shared__ float acc[2048];
    int fb = blockIdx.x, tid = threadIdx.x;
    acc[tid] = 0.f; acc[tid + 1024] = 0.f;
    __syncthreads();
    size_t pbase = (size_t)fb * CAP_F;
    int n = cur[fb] - (int)(fb * CAP_F);
    int k0 = 0;
    for (; k0 + 16384 <= n; k0 += 16384) {
        unsigned p[16];
        #pragma unroll
        for (int u = 0; u < 16; ++u)
            p[u] = __builtin_nontemporal_load(&pk1[pbase + k0 + tid + u * 1024]);
        unsigned raw[16];
        #pragma unroll
        for (int u = 0; u < 16; ++u) raw[u] = z3h[p[u] >> FBB];
        #pragma unroll
        for (int u = 0; u < 16; ++u) {
            float2 v = __half22float2(*(__half2*)&raw[u]);
            unsigned d = (p[u] & 1023u) << 1;
            atomicAdd(&acc[d], v.x);
            atomicAdd(&acc[d + 1], v.y);
        }
    }
    for (; k0 + 4096 <= n; k0 += 4096) {
        unsigned p[4];
        #pragma unroll
        for (int u = 0; u < 4; ++u)
            p[u] = __builtin_nontemporal_load(&pk1[pbase + k0 + tid + u * 1024]);
        unsigned raw[4];
        #pragma unroll
        for (int u = 0; u < 4; ++u) raw[u] = z3h[p[u] >> FBB];
        #pragma unroll
        for (int u = 0; u < 4; ++u) {
            float2 v = __half22float2(*(__half2*)&raw[u]);
            unsigned d = (p[u] & 1023u) << 1;
            atomicAdd(&acc[d], v.x);
            atomicAdd(&acc[d + 1], v.y);
        }
    }
    for (int k = k0 + tid; k < n; k += 1024) {
        unsigned p = __builtin_nontemporal_load(&pk1[pbase + k]);
        unsigned zr = z3h[p >> FBB];
        float2 v = __half22float2(*(__half2*)&zr);
        unsigned d = (p & 1023u) << 1;
        atomicAdd(&acc[d], v.x);
        atomicAdd(&acc[d + 1], v.y);
    }
    __syncthreads();
    int i = (fb << FBB) + tid;
    if (i < N) {
        unsigned zr = z3h[i];
        float2 zi = __half22float2(*(__half2*)&zr);
        float di = dinv[i];
        float a0 = acc[tid * 2] + zi.x;
        float a1 = acc[tid * 2 + 1] + zi.y;
        ((float2*)out)[i] = make_float2(fmaf(di, a0, b3[0]), fmaf(di, a1, b3[1]));
    }
}

extern "C" void kernel_launch(void* const* d_in, const int* in_sizes, int n_in,
                              void* d_out, int out_size, void* d_ws, size_t ws_size,
                              hipStream_t stream) {
    const float* x  = (const float*)d_in[0];
    const int*   ei = (const int*)d_in[1];
    const float* W1 = (const float*)d_in[2];
    const float* b1 = (const float*)d_in[3];
    const float* W2 = (const float*)d_in[4];
    const float* b2 = (const float*)d_in[5];
    const float* W3 = (const float*)d_in[6];
    const float* b3 = (const float*)d_in[7];
    float* out = (float*)d_out;

    const int N = in_sizes[0] / 2;
    const int E = in_sizes[1] / 2;
    const int* src = ei;
    const int* dst = ei + E;

    const int FB  = (N + (1 << FBB) - 1) >> FBB;     // 489 fine buckets
    const int ntB = (E + T_TILE - 1) / T_TILE;       // 977 tiles of 16K edges

    // ws layout (256B-aligned)
    auto align = [](size_t o) { return (o + 255) & ~(size_t)255; };
    char* wbase = (char*)d_ws;
    size_t off = 0;
    float*    dinv = (float*)(wbase + off);    off = align(off + (size_t)N * 4);
    unsigned* z1h  = (unsigned*)(wbase + off); off = align(off + (size_t)N * 4);
    unsigned long long* z2h = (unsigned long long*)(wbase + off);
    off = align(off + (size_t)N * 8);
    unsigned* z3h  = (unsigned*)(wbase + off); off = align(off + (size_t)N * 4);
    int*      cur  = (int*)(wbase + off);      off = align(off + (size_t)FB_MAX * 4);
    unsigned* pk1  = (unsigned*)(wbase + off); off = align(off + (size_t)FB * CAP_F * 4);

    initcur<<<dim3(1), dim3(512), 0, stream>>>(cur, FB);
    scatter1<<<dim3(ntB), dim3(512), 0, stream>>>(dst, src, cur, pk1, E, FB);
    builddeg<<<dim3(FB), dim3(1024), 0, stream>>>(pk1, cur, x, dinv, z1h, N);
    glayer1<<<dim3(FB), dim3(1024), 0, stream>>>(pk1, cur, z1h, dinv, W1, b1,
                                                 (uint2*)z2h, N);
    glayer2<<<dim3(FB), dim3(1024), 0, stream>>>(pk1, cur, z2h, dinv, W2, b2, W3,
                                                 z3h, N);
    glayer3<<<dim3(FB), dim3(1024), 0, stream>>>(pk1, cur, z3h, dinv, b3, out, N);
}

// Round 10
// 850.441 us; speedup vs baseline: 1.1624x; 1.1624x over previous
//
#include <hip/hip_runtime.h>
#include <hip/hip_fp16.h>

// GCN 3-layer, pull-mode layers + lean build (R21) + degree-sorted node
// permutation (R23).
// R19/R20/R22 push-mode all failed 2-3x (divergent-gather -> LDS-atomic
// chain stalls; gather -> VGPR accumulate is the only fast shape on gfx950).
// Layers sit at the per-XCD L2 random-request wall (~8.1us/M gathers; R17
// residency + R18 L1-bypass null). R23 attacks WAVE DIVERGENCE: degrees
// ~Poisson(32), wave pace = max-of-64 ~ 47 + ~15-iter masked tail. buildfine
// emits perm[] = nodes degree-sorted within each 1024-node bucket; layer
// thread i processes node perm[i] -> 64 same-degree nodes per wave, equal
// trip counts. rowptr/self/out accesses become random within a 4-8KB bucket
// window (L1/L2 hit); csr rows stay lane-contiguous (full-line use).
// Build (R21): initcur -> scatter1 (in-LDS counting sort into 489 fine
// buckets, atomic chunk reservation) -> bases_fix -> buildfine (degrees ->
// rowptr/dinv/z1 + in-LDS node sort -> csr + NEW degree-bin sort -> perm).
// R13: z2 4xfp16 (8B/node). R14: z1/z3 half2 (4B/node). gcn2 16-deep (R23).
// Math per layer (input u): z = u*dinv; s_i = sum_{e:dst=i} z[src_e];
//   out_i = (dinv_i*(s_i + z_i)) @ W + b   (self-loop folds into s+z).
// pk1 = (dst&1023) | (src<<10)  (29 bits, N < 2^19).

#define TPB 256
#define T_TILE 16384
#define FBB 10           // fine bucket = 1024 nodes
#define FB_MAX 512
#define CAP_F 34048      // per-bucket pk1 capacity: mean 32.7K, +7 sigma
#define EB_CAP 34048

// ---- init: bucket reservation cursors ----
__global__ void initcur(int* __restrict__ cur, int FB) {
    int t = threadIdx.x;
    if (t < FB) cur[t] = t * CAP_F;
}

// ---- pass 1: in-LDS counting-sort scatter into fine buckets (R21) ----
__global__ void __launch_bounds__(512)
scatter1(const int* __restrict__ dst, const int* __restrict__ src,
         int* __restrict__ cur, unsigned* __restrict__ pk1, int E, int FB) {
    __shared__ unsigned lpk[T_TILE];   // 64KB staged packed values
    __shared__ int lhist[FB_MAX];
    __shared__ int lexcl[FB_MAX];
    __shared__ int lcur[FB_MAX];
    __shared__ int lbase[FB_MAX];
    int blk = blockIdx.x, tid = threadIdx.x;
    lhist[tid] = 0;
    __syncthreads();
    int base = blk * T_TILE;
    // pass A: tile histogram over fine buckets (dst slice L2-hot for pass B)
    #pragma unroll 8
    for (int it = 0; it < T_TILE / 512; ++it) {
        int e = base + it * 512 + tid;
        if (e < E) atomicAdd(&lhist[((unsigned)dst[e]) >> FBB], 1);
    }
    __syncthreads();
    // exclusive scan over 512 bucket counts (FB=489 used)
    int hv = lhist[tid];
    lexcl[tid] = hv;
    __syncthreads();
    for (int off = 1; off < FB_MAX; off <<= 1) {
        int a = (tid >= off) ? lexcl[tid - off] : 0;
        __syncthreads();
        lexcl[tid] += a;
        __syncthreads();
    }
    lexcl[tid] -= hv;
    lcur[tid] = lexcl[tid];
    // reserve global chunk per bucket (one atomic per non-empty bucket)
    if (tid < FB && hv > 0) lbase[tid] = atomicAdd(&cur[tid], hv);
    __syncthreads();
    // pass B: place packed values into LDS at sorted positions
    #pragma unroll 8
    for (int it = 0; it < T_TILE / 512; ++it) {
        int e = base + it * 512 + tid;
        if (e < E) {
            unsigned d = (unsigned)dst[e];
            unsigned s = (unsigned)src[e];
            int pos = atomicAdd(&lcur[d >> FBB], 1);
            lpk[pos] = (d & 1023u) | (s << FBB);
        }
    }
    __syncthreads();
    // flush: wave-parallel per-bucket contiguous copy
    int w = tid >> 6, lane = tid & 63;
    for (int fb = w; fb < FB; fb += 8) {
        int cntb = lhist[fb];
        if (cntb == 0) continue;
        int lo = lexcl[fb], gb = lbase[fb];
        for (int t2 = lane; t2 < cntb; t2 += 64)
            pk1[gb + t2] = lpk[lo + t2];
    }
}

// ---- compact csr bases from final cursors (single block) ----
__global__ void bases_fix(const int* __restrict__ cur, int* __restrict__ csrbase,
                          int* __restrict__ rowptr, int FB, int N, int E) {
    __shared__ int lds[FB_MAX];
    int t = threadIdx.x;
    int c = (t < FB) ? (cur[t] - t * CAP_F) : 0;
    lds[t] = c;
    __syncthreads();
    for (int off = 1; off < FB_MAX; off <<= 1) {
        int a = (t >= off) ? lds[t - off] : 0;
        __syncthreads();
        lds[t] += a;
        __syncthreads();
    }
    if (t < FB) csrbase[t] = lds[t] - c;  // exclusive
    if (t == 0) { csrbase[FB] = E; rowptr[N] = E; }
}

// ---- pass 2: per-fine-bucket node sort -> csr + rowptr + dinv + z1 + perm ----
__global__ void __launch_bounds__(1024)
buildfine(const unsigned* __restrict__ pk1, const int* __restrict__ csrbase,
          const float* __restrict__ x, int* __restrict__ rowptr,
          float* __restrict__ dinv, unsigned* __restrict__ z1h,
          unsigned* __restrict__ csr, int* __restrict__ perm, int N) {
    __shared__ int cnt[1024];
    __shared__ int tmp[1024];
    __shared__ int cur[1024];
    __shared__ unsigned eb[EB_CAP];
    __shared__ int dh[128];
    __shared__ int dcur[128];
    int fb = blockIdx.x, tid = threadIdx.x;
    int cb = csrbase[fb];
    int n = csrbase[fb + 1] - cb;
    size_t pbase = (size_t)fb * CAP_F;
    cnt[tid] = 0;
    if (tid < 128) dh[tid] = 0;
    __syncthreads();
    // pass A: per-node degree
    int k0 = 0;
    for (; k0 + 8192 <= n; k0 += 8192) {
        unsigned p[8];
        #pragma unroll
        for (int u = 0; u < 8; ++u) p[u] = pk1[pbase + k0 + tid + u * 1024];
        #pragma unroll
        for (int u = 0; u < 8; ++u) atomicAdd(&cnt[p[u] & 1023u], 1);
    }
    for (int k = k0 + tid; k < n; k += 1024)
        atomicAdd(&cnt[pk1[pbase + k] & 1023u], 1);
    __syncthreads();
    // scan 1024 node counts
    int c = cnt[tid];
    tmp[tid] = c;
    __syncthreads();
    for (int o = 1; o < 1024; o <<= 1) {
        int a = (tid >= o) ? tmp[tid - o] : 0;
        __syncthreads();
        tmp[tid] += a;
        __syncthreads();
    }
    int excl = tmp[tid] - c;
    int i = (fb << FBB) + tid;
    if (i < N) {
        rowptr[i] = cb + excl;
        float di = rsqrtf((float)c + 1.0f);
        dinv[i] = di;
        float2 xv = ((const float2*)x)[i];
        __half2 hz = __floats2half2_rn(xv.x * di, xv.y * di);
        z1h[i] = *(unsigned*)&hz;
    }
    cur[tid] = excl;
    // degree-bin histogram for perm (valid nodes only)
    int dcap = (c < 127) ? c : 127;
    if (i < N) atomicAdd(&dh[dcap], 1);
    __syncthreads();
    // scan 128 degree bins
    if (tid < 128) dcur[tid] = dh[tid];
    __syncthreads();
    for (int o = 1; o < 128; o <<= 1) {
        int a = (tid < 128 && tid >= o) ? dcur[tid - o] : 0;
        __syncthreads();
        if (tid < 128) dcur[tid] += a;
        __syncthreads();
    }
    if (tid < 128) dcur[tid] -= dh[tid];  // exclusive
    __syncthreads();
    if (i < N) {
        int r = atomicAdd(&dcur[dcap], 1);
        perm[(fb << FBB) + r] = i;
    }
    __syncthreads();
    // pass B: place srcs sorted by node
    if (n <= EB_CAP) {
        k0 = 0;
        for (; k0 + 8192 <= n; k0 += 8192) {
            unsigned p[8];
            #pragma unroll
            for (int u = 0; u < 8; ++u) p[u] = pk1[pbase + k0 + tid + u * 1024];
            #pragma unroll
            for (int u = 0; u < 8; ++u) {
                int pos = atomicAdd(&cur[p[u] & 1023u], 1);
                eb[pos] = p[u] >> FBB;
            }
        }
        for (int k = k0 + tid; k < n; k += 1024) {
            unsigned p = pk1[pbase + k];
            int pos = atomicAdd(&cur[p & 1023u], 1);
            eb[pos] = p >> FBB;
        }
        __syncthreads();
        for (int k = tid; k < n; k += 1024) csr[cb + k] = eb[k];
    } else {
        for (int k = tid; k < n; k += 1024) {
            unsigned p = pk1[pbase + k];
            int pos = atomicAdd(&cur[p & 1023u], 1);
            csr[cb + pos] = p >> FBB;
        }
    }
}

// ---------------- GCN layers (pull, degree-sorted perm) ----------------

__global__ void gcn1(const int* __restrict__ rowptr, const unsigned* __restrict__ csr,
                     const int* __restrict__ perm,
                     const unsigned* __restrict__ z1h, const float* __restrict__ W1,
                     const float* __restrict__ b1, const float* __restrict__ dinv,
                     uint2* __restrict__ z2h, int N) {
    int ii = blockIdx.x * blockDim.x + threadIdx.x;
    if (ii >= N) return;
    int i = perm[ii];
    int r0 = rowptr[i], r1 = rowptr[i + 1];
    float a0, a1;
    {
        unsigned zr = z1h[i];
        float2 zi = __half22float2(*(__half2*)&zr);
        a0 = zi.x; a1 = zi.y;
    }
    int k = r0;
    for (; k + 16 <= r1; k += 16) {
        unsigned j[16];
        #pragma unroll
        for (int u = 0; u < 16; ++u) j[u] = __builtin_nontemporal_load(&csr[k + u]);
        unsigned raw[16];
        #pragma unroll
        for (int u = 0; u < 16; ++u) raw[u] = z1h[j[u]];
        #pragma unroll
        for (int u = 0; u < 16; ++u) {
            float2 v = __half22float2(*(__half2*)&raw[u]);
            a0 += v.x; a1 += v.y;
        }
    }
    for (; k < r1; ++k) {
        unsigned zr = z1h[csr[k]];
        float2 zv = __half22float2(*(__half2*)&zr);
        a0 += zv.x; a1 += zv.y;
    }
    float di = dinv[i];
    float g0 = di * a0, g1 = di * a1;
    float o0 = di * tanhf(fmaf(g0, W1[0], fmaf(g1, W1[4], b1[0])));
    float o1 = di * tanhf(fmaf(g0, W1[1], fmaf(g1, W1[5], b1[1])));
    float o2 = di * tanhf(fmaf(g0, W1[2], fmaf(g1, W1[6], b1[2])));
    float o3 = di * tanhf(fmaf(g0, W1[3], fmaf(g1, W1[7], b1[3])));
    __half2 ha = __floats2half2_rn(o0, o1);
    __half2 hb = __floats2half2_rn(o2, o3);
    uint2 packed;
    packed.x = *(unsigned*)&ha;
    packed.y = *(unsigned*)&hb;
    z2h[i] = packed;
}

__global__ void gcn2(const int* __restrict__ rowptr, const unsigned* __restrict__ csr,
                     const int* __restrict__ perm,
                     const uint2* __restrict__ z2h, const float* __restrict__ W2,
                     const float* __restrict__ b2, const float* __restrict__ W3,
                     const float* __restrict__ dinv, unsigned* __restrict__ z3h, int N) {
    int ii = blockIdx.x * blockDim.x + threadIdx.x;
    if (ii >= N) return;
    int i = perm[ii];
    int r0 = rowptr[i], r1 = rowptr[i + 1];
    float a0, a1, a2, a3;
    {
        uint2 raw = z2h[i];
        float2 f01 = __half22float2(*(__half2*)&raw.x);
        float2 f23 = __half22float2(*(__half2*)&raw.y);
        a0 = f01.x; a1 = f01.y; a2 = f23.x; a3 = f23.y;
    }
    int k = r0;
    for (; k + 16 <= r1; k += 16) {
        unsigned j[16];
        #pragma unroll
        for (int u = 0; u < 16; ++u) j[u] = __builtin_nontemporal_load(&csr[k + u]);
        uint2 raw[16];
        #pragma unroll
        for (int u = 0; u < 16; ++u) raw[u] = z2h[j[u]];
        #pragma unroll
        for (int u = 0; u < 16; ++u) {
            float2 f01 = __half22float2(*(__half2*)&raw[u].x);
            float2 f23 = __half22float2(*(__half2*)&raw[u].y);
            a0 += f01.x; a1 += f01.y; a2 += f23.x; a3 += f23.y;
        }
    }
    for (; k < r1; ++k) {
        uint2 raw = z2h[csr[k]];
        float2 f01 = __half22float2(*(__half2*)&raw.x);
        float2 f23 = __half22float2(*(__half2*)&raw.y);
        a0 += f01.x; a1 += f01.y; a2 += f23.x; a3 += f23.y;
    }
    float di = dinv[i];
    float g0 = di * a0, g1 = di * a1, g2 = di * a2, g3 = di * a3;
    float h[4];
    #pragma unroll
    for (int c = 0; c < 4; ++c)
        h[c] = tanhf(b2[c] + g0 * W2[c] + g1 * W2[4 + c] + g2 * W2[8 + c] + g3 * W2[12 + c]);
    float v0 = h[0] * W3[0] + h[1] * W3[2] + h[2] * W3[4] + h[3] * W3[6];
    float v1 = h[0] * W3[1] + h[1] * W3[3] + h[2] * W3[5] + h[3] * W3[7];
    __half2 hz = __floats2half2_rn(v0 * di, v1 * di);
    z3h[i] = *(unsigned*)&hz;
}

__global__ void gcn3(const int* __restrict__ rowptr, const unsigned* __restrict__ csr,
                     const int* __restrict__ perm,
                     const unsigned* __restrict__ z3h, const float* __restrict__ b3,
                     const float* __restrict__ dinv, float* __restrict__ out, int N) {
    int ii = blockIdx.x * blockDim.x + threadIdx.x;
    if (ii >= N) return;
    int i = perm[ii];
    int r0 = rowptr[i], r1 = rowptr[i + 1];
    float a0, a1;
    {
        unsigned zr = z3h[i];
        float2 zi = __half22float2(*(__half2*)&zr);
        a0 = zi.x; a1 = zi.y;
    }
    int k = r0;
    for (; k + 16 <= r1; k += 16) {
        unsigned j[16];
        #pragma unroll
        for (int u = 0; u < 16; ++u) j[u] = __builtin_nontemporal_load(&csr[k + u]);
        unsigned raw[16];
        #pragma unroll
        for (int u = 0; u < 16; ++u) raw[u] = z3h[j[u]];
        #pragma unroll
        for (int u = 0; u < 16; ++u) {
            float2 v = __half22float2(*(__half2*)&raw[u]);
            a0 += v.x; a1 += v.y;
        }
    }
    for (; k < r1; ++k) {
        unsigned zr = z3h[csr[k]];
        float2 zv = __half22float2(*(__half2*)&zr);
        a0 += zv.x; a1 += zv.y;
    }
    float di = dinv[i];
    ((float2*)out)[i] = make_float2(fmaf(di, a0, b3[0]), fmaf(di, a1, b3[1]));
}

extern "C" void kernel_launch(void* const* d_in, const int* in_sizes, int n_in,
                              void* d_out, int out_size, void* d_ws, size_t ws_size,
                              hipStream_t stream) {
    const float* x  = (const float*)d_in[0];
    const int*   ei = (const int*)d_in[1];
    const float* W1 = (const float*)d_in[2];
    const float* b1 = (const float*)d_in[3];
    const float* W2 = (const float*)d_in[4];
    const float* b2 = (const float*)d_in[5];
    const float* W3 = (const float*)d_in[6];
    const float* b3 = (const float*)d_in[7];
    float* out = (float*)d_out;

    const int N = in_sizes[0] / 2;
    const int E = in_sizes[1] / 2;
    const int* src = ei;
    const int* dst = ei + E;

    const int FB  = (N + (1 << FBB) - 1) >> FBB;     // 489 fine buckets
    const int ntB = (E + T_TILE - 1) / T_TILE;       // 977 tiles of 16K edges

    // ws layout (256B-aligned)
    auto align = [](size_t o) { return (o + 255) & ~(size_t)255; };
    char* wbase = (char*)d_ws;
    size_t off = 0;
    float*    dinv    = (float*)(wbase + off);    off = align(off + (size_t)N * 4);
    unsigned* z1h     = (unsigned*)(wbase + off); off = align(off + (size_t)N * 4);
    uint2*    z2h     = (uint2*)(wbase + off);    off = align(off + (size_t)N * 8);
    unsigned* z3h     = (unsigned*)(wbase + off); off = align(off + (size_t)N * 4);
    int*      rowptr  = (int*)(wbase + off);      off = align(off + (size_t)(N + 1) * 4);
    int*      perm    = (int*)(wbase + off);      off = align(off + (size_t)N * 4);
    int*      cur     = (int*)(wbase + off);      off = align(off + (size_t)FB_MAX * 4);
    int*      csrbase = (int*)(wbase + off);      off = align(off + (size_t)(FB_MAX + 1) * 4);
    unsigned* pk1     = (unsigned*)(wbase + off); off = align(off + (size_t)FB * CAP_F * 4);
    unsigned* csr     = (unsigned*)(wbase + off); off = align(off + (size_t)E * 4);

    dim3 gN((N + TPB - 1) / TPB);
    initcur<<<dim3(1), dim3(512), 0, stream>>>(cur, FB);
    scatter1<<<dim3(ntB), dim3(512), 0, stream>>>(dst, src, cur, pk1, E, FB);
    bases_fix<<<dim3(1), dim3(512), 0, stream>>>(cur, csrbase, rowptr, FB, N, E);
    buildfine<<<dim3(FB), dim3(1024), 0, stream>>>(pk1, csrbase, x, rowptr, dinv,
                                                   z1h, csr, perm, N);
    gcn1<<<gN, dim3(TPB), 0, stream>>>(rowptr, csr, perm, z1h, W1, b1, dinv, z2h, N);
    gcn2<<<gN, dim3(TPB), 0, stream>>>(rowptr, csr, perm, z2h, W2, b2, W3, dinv, z3h, N);
    gcn3<<<gN, dim3(TPB), 0, stream>>>(rowptr, csr, perm, z3h, b3, dinv, out, N);
}

// Round 12
// 816.115 us; speedup vs baseline: 1.2112x; 1.0421x over previous
//
#include <hip/hip_runtime.h>
#include <hip/hip_fp16.h>

// GCN 3-layer, pull-mode layers (R21-proven, 715us) + faster build (R24b).
// History: push-mode (R19/R20/R22) 2-3x worse (gather->LDS-atomic stalls);
// R23 perm + deep unroll regressed (FETCH 325->536MB: more outstanding
// randoms thrash the exactly-L2-sized table; scattered writes). Layers are
// AT the per-XCD L2 request-service wall (~8.1us/M gathers ~ 6.4 req/cyc/
// XCD); R17 residency, R18 L1-bypass all null. 48M gathers -> ~405us floor.
// R24 recovers build slack (~306us vs ~80us traffic floor):
// - scatter1: T_TILE 32K (static 128KB lpk), wave-shuffle scans (~3 barriers
//   vs ~21), linear binary-search flush (fully coalesced writes).
// - buildfine: wave-shuffle scan (3 barriers vs ~20).
// R24b: fix compile — scan temp renamed sv (was x, collided with param x).
// Build: initcur -> scatter1 (in-LDS counting sort into 489 fine buckets of
// 1024 nodes, atomic chunk reservation into pk1[fb*CAP_F..]) -> bases_fix ->
// buildfine (degrees -> rowptr/dinv/z1 + in-LDS node sort -> csr).
// R13: z2 4xfp16 (8B/node). R14: z1/z3 half2 (4B/node).
// Math per layer (input u): z = u*dinv; s_i = sum_{e:dst=i} z[src_e];
//   out_i = (dinv_i*(s_i + z_i)) @ W + b   (self-loop folds into s+z).
// pk1 = (dst&1023) | (src<<10)  (29 bits, N < 2^19).

#define TPB 256
#define T_TILE 32768
#define FBB 10           // fine bucket = 1024 nodes
#define FB_MAX 512
#define CAP_F 34048      // per-bucket pk1 capacity: mean 32768, +7 sigma
#define EB_CAP 34048

// ---- init: bucket reservation cursors ----
__global__ void initcur(int* __restrict__ cur, int FB) {
    int t = threadIdx.x;
    if (t < FB) cur[t] = t * CAP_F;
}

// ---- pass 1: in-LDS counting-sort scatter into fine buckets ----
__global__ void __launch_bounds__(512)
scatter1(const int* __restrict__ dst, const int* __restrict__ src,
         int* __restrict__ cur, unsigned* __restrict__ pk1, int E, int FB) {
    __shared__ unsigned lpk[T_TILE];   // 128KB staged packed values
    __shared__ int lhist[FB_MAX];
    __shared__ int lexcl[FB_MAX];
    __shared__ int lcur[FB_MAX];
    __shared__ int lbase[FB_MAX];
    __shared__ int wsum[8];
    int blk = blockIdx.x, tid = threadIdx.x;
    int lane = tid & 63, w = tid >> 6;
    lhist[tid] = 0;
    __syncthreads();
    int base = blk * T_TILE;
    int ntile = (E - base < T_TILE) ? (E - base) : T_TILE;
    // pass A: tile histogram over fine buckets (dst slice L2-hot for pass B)
    #pragma unroll 8
    for (int it = 0; it < T_TILE / 512; ++it) {
        int e = base + it * 512 + tid;
        if (e < E) atomicAdd(&lhist[((unsigned)dst[e]) >> FBB], 1);
    }
    __syncthreads();
    // wave-shuffle exclusive scan over 512 bucket counts
    int hv = lhist[tid];
    int sv = hv;
    #pragma unroll
    for (int d = 1; d < 64; d <<= 1) {
        int sy = __shfl_up(sv, d, 64);
        if (lane >= d) sv += sy;
    }
    if (lane == 63) wsum[w] = sv;
    __syncthreads();
    if (tid < 64) {
        int s = (tid < 8) ? wsum[tid] : 0;
        #pragma unroll
        for (int d = 1; d < 8; d <<= 1) {
            int sy = __shfl_up(s, d, 64);
            if (tid >= d) s += sy;
        }
        if (tid < 8) wsum[tid] = s;
    }
    __syncthreads();
    int excl = ((w > 0) ? wsum[w - 1] : 0) + sv - hv;
    lexcl[tid] = excl;
    lcur[tid] = excl;
    // reserve global chunk per bucket (one atomic per non-empty bucket)
    if (tid < FB && hv > 0) lbase[tid] = atomicAdd(&cur[tid], hv);
    __syncthreads();
    // pass B: place packed values into LDS at sorted positions
    #pragma unroll 8
    for (int it = 0; it < T_TILE / 512; ++it) {
        int e = base + it * 512 + tid;
        if (e < E) {
            unsigned d = (unsigned)dst[e];
            unsigned s = (unsigned)src[e];
            int pos = atomicAdd(&lcur[d >> FBB], 1);
            lpk[pos] = (d & 1023u) | (s << FBB);
        }
    }
    __syncthreads();
    // flush: linear coalesced walk; binary search lexcl for owning bucket
    for (int k = tid; k < ntile; k += 512) {
        int lo = 0, hi = FB - 1;
        while (lo < hi) {
            int mid = (lo + hi + 1) >> 1;
            if (lexcl[mid] <= k) lo = mid; else hi = mid - 1;
        }
        pk1[lbase[lo] + (k - lexcl[lo])] = lpk[k];
    }
}

// ---- compact csr bases from final cursors (single block) ----
__global__ void bases_fix(const int* __restrict__ cur, int* __restrict__ csrbase,
                          int* __restrict__ rowptr, int FB, int N, int E) {
    __shared__ int lds[FB_MAX];
    int t = threadIdx.x;
    int c = (t < FB) ? (cur[t] - t * CAP_F) : 0;
    lds[t] = c;
    __syncthreads();
    for (int off = 1; off < FB_MAX; off <<= 1) {
        int a = (t >= off) ? lds[t - off] : 0;
        __syncthreads();
        lds[t] += a;
        __syncthreads();
    }
    if (t < FB) csrbase[t] = lds[t] - c;  // exclusive
    if (t == 0) { csrbase[FB] = E; rowptr[N] = E; }
}

// ---- pass 2: per-fine-bucket node sort -> csr + rowptr + dinv + z1 ----
__global__ void __launch_bounds__(1024)
buildfine(const unsigned* __restrict__ pk1, const int* __restrict__ csrbase,
          const float* __restrict__ x, int* __restrict__ rowptr,
          float* __restrict__ dinv, unsigned* __restrict__ z1h,
          unsigned* __restrict__ csr, int N) {
    __shared__ int cnt[1024];
    __shared__ int cur[1024];
    __shared__ unsigned eb[EB_CAP];
    __shared__ int wsum[16];
    int fb = blockIdx.x, tid = threadIdx.x;
    int lane = tid & 63, w = tid >> 6;
    int cb = csrbase[fb];
    int n = csrbase[fb + 1] - cb;
    size_t pbase = (size_t)fb * CAP_F;
    cnt[tid] = 0;
    __syncthreads();
    // pass A: per-node degree
    int k0 = 0;
    for (; k0 + 8192 <= n; k0 += 8192) {
        unsigned p[8];
        #pragma unroll
        for (int u = 0; u < 8; ++u) p[u] = pk1[pbase + k0 + tid + u * 1024];
        #pragma unroll
        for (int u = 0; u < 8; ++u) atomicAdd(&cnt[p[u] & 1023u], 1);
    }
    for (int k = k0 + tid; k < n; k += 1024)
        atomicAdd(&cnt[pk1[pbase + k] & 1023u], 1);
    __syncthreads();
    // wave-shuffle exclusive scan over 1024 node counts
    int c = cnt[tid];
    int sv = c;
    #pragma unroll
    for (int d = 1; d < 64; d <<= 1) {
        int sy = __shfl_up(sv, d, 64);
        if (lane >= d) sv += sy;
    }
    if (lane == 63) wsum[w] = sv;
    __syncthreads();
    if (tid < 64) {
        int s = (tid < 16) ? wsum[tid] : 0;
        #pragma unroll
        for (int d = 1; d < 16; d <<= 1) {
            int sy = __shfl_up(s, d, 64);
            if (tid >= d) s += sy;
        }
        if (tid < 16) wsum[tid] = s;
    }
    __syncthreads();
    int excl = ((w > 0) ? wsum[w - 1] : 0) + sv - c;
    int i = (fb << FBB) + tid;
    if (i < N) {
        rowptr[i] = cb + excl;
        float di = rsqrtf((float)c + 1.0f);
        dinv[i] = di;
        float2 xv = ((const float2*)x)[i];
        __half2 hz = __floats2half2_rn(xv.x * di, xv.y * di);
        z1h[i] = *(unsigned*)&hz;
    }
    cur[tid] = excl;
    __syncthreads();
    // pass B: place srcs sorted by node (bucket region is L2-warm)
    if (n <= EB_CAP) {
        k0 = 0;
        for (; k0 + 8192 <= n; k0 += 8192) {
            unsigned p[8];
            #pragma unroll
            for (int u = 0; u < 8; ++u) p[u] = pk1[pbase + k0 + tid + u * 1024];
            #pragma unroll
            for (int u = 0; u < 8; ++u) {
                int pos = atomicAdd(&cur[p[u] & 1023u], 1);
                eb[pos] = p[u] >> FBB;
            }
        }
        for (int k = k0 + tid; k < n; k += 1024) {
            unsigned p = pk1[pbase + k];
            int pos = atomicAdd(&cur[p & 1023u], 1);
            eb[pos] = p >> FBB;
        }
        __syncthreads();
        for (int k = tid; k < n; k += 1024) csr[cb + k] = eb[k];
    } else {
        for (int k = tid; k < n; k += 1024) {
            unsigned p = pk1[pbase + k];
            int pos = atomicAdd(&cur[p & 1023u], 1);
            csr[cb + pos] = p >> FBB;
        }
    }
}

// ---------------- GCN layers (R21-proven pull mode) ----------------

__global__ void gcn1(const int* __restrict__ rowptr, const unsigned* __restrict__ csr,
                     const unsigned* __restrict__ z1h, const float* __restrict__ W1,
                     const float* __restrict__ b1, const float* __restrict__ dinv,
                     uint2* __restrict__ z2h, int N) {
    int i = blockIdx.x * blockDim.x + threadIdx.x;
    if (i >= N) return;
    int r0 = rowptr[i], r1 = rowptr[i + 1];
    float a0, a1;
    {
        unsigned zr = z1h[i];
        float2 zi = __half22float2(*(__half2*)&zr);
        a0 = zi.x; a1 = zi.y;
    }
    int k = r0;
    for (; k + 16 <= r1; k += 16) {
        unsigned j[16];
        #pragma unroll
        for (int u = 0; u < 16; ++u) j[u] = __builtin_nontemporal_load(&csr[k + u]);
        unsigned raw[16];
        #pragma unroll
        for (int u = 0; u < 16; ++u) raw[u] = z1h[j[u]];
        #pragma unroll
        for (int u = 0; u < 16; ++u) {
            float2 v = __half22float2(*(__half2*)&raw[u]);
            a0 += v.x; a1 += v.y;
        }
    }
    for (; k < r1; ++k) {
        unsigned zr = z1h[csr[k]];
        float2 zv = __half22float2(*(__half2*)&zr);
        a0 += zv.x; a1 += zv.y;
    }
    float di = dinv[i];
    float g0 = di * a0, g1 = di * a1;
    float o0 = di * tanhf(fmaf(g0, W1[0], fmaf(g1, W1[4], b1[0])));
    float o1 = di * tanhf(fmaf(g0, W1[1], fmaf(g1, W1[5], b1[1])));
    float o2 = di * tanhf(fmaf(g0, W1[2], fmaf(g1, W1[6], b1[2])));
    float o3 = di * tanhf(fmaf(g0, W1[3], fmaf(g1, W1[7], b1[3])));
    __half2 ha = __floats2half2_rn(o0, o1);
    __half2 hb = __floats2half2_rn(o2, o3);
    uint2 packed;
    packed.x = *(unsigned*)&ha;
    packed.y = *(unsigned*)&hb;
    z2h[i] = packed;
}

__global__ void gcn2(const int* __restrict__ rowptr, const unsigned* __restrict__ csr,
                     const uint2* __restrict__ z2h, const float* __restrict__ W2,
                     const float* __restrict__ b2, const float* __restrict__ W3,
                     const float* __restrict__ dinv, unsigned* __restrict__ z3h, int N) {
    int i = blockIdx.x * blockDim.x + threadIdx.x;
    if (i >= N) return;
    int r0 = rowptr[i], r1 = rowptr[i + 1];
    float a0, a1, a2, a3;
    {
        uint2 raw = z2h[i];
        float2 f01 = __half22float2(*(__half2*)&raw.x);
        float2 f23 = __half22float2(*(__half2*)&raw.y);
        a0 = f01.x; a1 = f01.y; a2 = f23.x; a3 = f23.y;
    }
    int k = r0;
    for (; k + 8 <= r1; k += 8) {
        unsigned j[8];
        #pragma unroll
        for (int u = 0; u < 8; ++u) j[u] = __builtin_nontemporal_load(&csr[k + u]);
        uint2 raw[8];
        #pragma unroll
        for (int u = 0; u < 8; ++u) raw[u] = z2h[j[u]];
        #pragma unroll
        for (int u = 0; u < 8; ++u) {
            float2 f01 = __half22float2(*(__half2*)&raw[u].x);
            float2 f23 = __half22float2(*(__half2*)&raw[u].y);
            a0 += f01.x; a1 += f01.y; a2 += f23.x; a3 += f23.y;
        }
    }
    for (; k < r1; ++k) {
        uint2 raw = z2h[csr[k]];
        float2 f01 = __half22float2(*(__half2*)&raw.x);
        float2 f23 = __half22float2(*(__half2*)&raw.y);
        a0 += f01.x; a1 += f01.y; a2 += f23.x; a3 += f23.y;
    }
    float di = dinv[i];
    float g0 = di * a0, g1 = di * a1, g2 = di * a2, g3 = di * a3;
    float h[4];
    #pragma unroll
    for (int c = 0; c < 4; ++c)
        h[c] = tanhf(b2[c] + g0 * W2[c] + g1 * W2[4 + c] + g2 * W2[8 + c] + g3 * W2[12 + c]);
    float v0 = h[0] * W3[0] + h[1] * W3[2] + h[2] * W3[4] + h[3] * W3[6];
    float v1 = h[0] * W3[1] + h[1] * W3[3] + h[2] * W3[5] + h[3] * W3[7];
    __half2 hz = __floats2half2_rn(v0 * di, v1 * di);
    z3h[i] = *(unsigned*)&hz;
}

__global__ void gcn3(const int* __restrict__ rowptr, const unsigned* __restrict__ csr,
                     const unsigned* __restrict__ z3h, const float* __restrict__ b3,
                     const float* __restrict__ dinv, float* __restrict__ out, int N) {
    int i = blockIdx.x * blockDim.x + threadIdx.x;
    if (i >= N) return;
    int r0 = rowptr[i], r1 = rowptr[i + 1];
    float a0, a1;
    {
        unsigned zr = z3h[i];
        float2 zi = __half22float2(*(__half2*)&zr);
        a0 = zi.x; a1 = zi.y;
    }
    int k = r0;
    for (; k + 16 <= r1; k += 16) {
        unsigned j[16];
        #pragma unroll
        for (int u = 0; u < 16; ++u) j[u] = __builtin_nontemporal_load(&csr[k + u]);
        unsigned raw[16];
        #pragma unroll
        for (int u = 0; u < 16; ++u) raw[u] = z3h[j[u]];
        #pragma unroll
        for (int u = 0; u < 16; ++u) {
            float2 v = __half22float2(*(__half2*)&raw[u]);
            a0 += v.x; a1 += v.y;
        }
    }
    for (; k < r1; ++k) {
        unsigned zr = z3h[csr[k]];
        float2 zv = __half22float2(*(__half2*)&zr);
        a0 += zv.x; a1 += zv.y;
    }
    float di = dinv[i];
    ((float2*)out)[i] = make_float2(fmaf(di, a0, b3[0]), fmaf(di, a1, b3[1]));
}

extern "C" void kernel_launch(void* const* d_in, const int* in_sizes, int n_in,
                              void* d_out, int out_size, void* d_ws, size_t ws_size,
                              hipStream_t stream) {
    const float* x  = (const float*)d_in[0];
    const int*   ei = (const int*)d_in[1];
    const float* W1 = (const float*)d_in[2];
    const float* b1 = (const float*)d_in[3];
    const float* W2 = (const float*)d_in[4];
    const float* b2 = (const float*)d_in[5];
    const float* W3 = (const float*)d_in[6];
    const float* b3 = (const float*)d_in[7];
    float* out = (float*)d_out;

    const int N = in_sizes[0] / 2;
    const int E = in_sizes[1] / 2;
    const int* src = ei;
    const int* dst = ei + E;

    const int FB  = (N + (1 << FBB) - 1) >> FBB;     // 489 fine buckets
    const int ntB = (E + T_TILE - 1) / T_TILE;       // 489 tiles of 32K edges

    // ws layout (256B-aligned)
    auto align = [](size_t o) { return (o + 255) & ~(size_t)255; };
    char* wbase = (char*)d_ws;
    size_t off = 0;
    float*    dinv    = (float*)(wbase + off);    off = align(off + (size_t)N * 4);
    unsigned* z1h     = (unsigned*)(wbase + off); off = align(off + (size_t)N * 4);
    uint2*    z2h     = (uint2*)(wbase + off);    off = align(off + (size_t)N * 8);
    unsigned* z3h     = (unsigned*)(wbase + off); off = align(off + (size_t)N * 4);
    int*      rowptr  = (int*)(wbase + off);      off = align(off + (size_t)(N + 1) * 4);
    int*      cur     = (int*)(wbase + off);      off = align(off + (size_t)FB_MAX * 4);
    int*      csrbase = (int*)(wbase + off);      off = align(off + (size_t)(FB_MAX + 1) * 4);
    unsigned* pk1     = (unsigned*)(wbase + off); off = align(off + (size_t)FB * CAP_F * 4);
    unsigned* csr     = (unsigned*)(wbase + off); off = align(off + (size_t)E * 4);

    dim3 gN((N + TPB - 1) / TPB);
    initcur<<<dim3(1), dim3(512), 0, stream>>>(cur, FB);
    scatter1<<<dim3(ntB), dim3(512), 0, stream>>>(dst, src, cur, pk1, E, FB);
    bases_fix<<<dim3(1), dim3(512), 0, stream>>>(cur, csrbase, rowptr, FB, N, E);
    buildfine<<<dim3(FB), dim3(1024), 0, stream>>>(pk1, csrbase, x, rowptr, dinv,
                                                   z1h, csr, N);
    gcn1<<<gN, dim3(TPB), 0, stream>>>(rowptr, csr, z1h, W1, b1, dinv, z2h, N);
    gcn2<<<gN, dim3(TPB), 0, stream>>>(rowptr, csr, z2h, W2, b2, W3, dinv, z3h, N);
    gcn3<<<gN, dim3(TPB), 0, stream>>>(rowptr, csr, z3h, b3, dinv, out, N);
}

// Round 13
// 711.337 us; speedup vs baseline: 1.3897x; 1.1473x over previous
//
#include <hip/hip_runtime.h>
#include <hip/hip_fp16.h>

// GCN 3-layer, pull-mode layers (R21-proven) + R21 build with wave-shuffle
// scans (R25 = R21 + scan-swap only).
// R24b regression post-mortem: 128KB lpk -> 1 block/CU (occ 22%) and
// binary-search flush -> 3.8M LDS bank conflicts + 17% VALU; both reverted.
// Wave-shuffle scans kept (3 barriers vs ~20; uninvolved in regression).
// History: push-mode (R19/R20/R22) 2-3x worse; R23 perm/deep-unroll thrashed
// L2 (FETCH 325->536MB). Layers are AT the per-XCD L2 request-service wall
// (~8.1us/M gathers; R17 residency + R18 L1-bypass null): 48M gathers ->
// ~405us floor. Build floor ~290us is dominated by 32M LDS atomics
// (histogram + placement), shared by all working variants.
// Build: initcur -> scatter1 (in-LDS counting sort into 489 fine buckets of
// 1024 nodes, atomic chunk reservation into pk1[fb*CAP_F..]) -> bases_fix ->
// buildfine (degrees -> rowptr/dinv/z1 + in-LDS node sort -> csr).
// R13: z2 4xfp16 (8B/node). R14: z1/z3 half2 (4B/node).
// Math per layer (input u): z = u*dinv; s_i = sum_{e:dst=i} z[src_e];
//   out_i = (dinv_i*(s_i + z_i)) @ W + b   (self-loop folds into s+z).
// pk1 = (dst&1023) | (src<<10)  (29 bits, N < 2^19).

#define TPB 256
#define T_TILE 16384
#define FBB 10           // fine bucket = 1024 nodes
#define FB_MAX 512
#define CAP_F 34048      // per-bucket pk1 capacity: mean 32768, +7 sigma
#define EB_CAP 34048

// ---- init: bucket reservation cursors ----
__global__ void initcur(int* __restrict__ cur, int FB) {
    int t = threadIdx.x;
    if (t < FB) cur[t] = t * CAP_F;
}

// ---- pass 1: in-LDS counting-sort scatter into fine buckets ----
__global__ void __launch_bounds__(512)
scatter1(const int* __restrict__ dst, const int* __restrict__ src,
         int* __restrict__ cur, unsigned* __restrict__ pk1, int E, int FB) {
    __shared__ unsigned lpk[T_TILE];   // 64KB staged packed values
    __shared__ int lhist[FB_MAX];
    __shared__ int lexcl[FB_MAX];
    __shared__ int lcur[FB_MAX];
    __shared__ int lbase[FB_MAX];
    __shared__ int wsum[8];
    int blk = blockIdx.x, tid = threadIdx.x;
    int lane = tid & 63, w = tid >> 6;
    lhist[tid] = 0;
    __syncthreads();
    int base = blk * T_TILE;
    // pass A: tile histogram over fine buckets (dst slice L2-hot for pass B)
    #pragma unroll 8
    for (int it = 0; it < T_TILE / 512; ++it) {
        int e = base + it * 512 + tid;
        if (e < E) atomicAdd(&lhist[((unsigned)dst[e]) >> FBB], 1);
    }
    __syncthreads();
    // wave-shuffle exclusive scan over 512 bucket counts
    int hv = lhist[tid];
    int sv = hv;
    #pragma unroll
    for (int d = 1; d < 64; d <<= 1) {
        int sy = __shfl_up(sv, d, 64);
        if (lane >= d) sv += sy;
    }
    if (lane == 63) wsum[w] = sv;
    __syncthreads();
    if (tid < 64) {
        int s = (tid < 8) ? wsum[tid] : 0;
        #pragma unroll
        for (int d = 1; d < 8; d <<= 1) {
            int sy = __shfl_up(s, d, 64);
            if (tid >= d) s += sy;
        }
        if (tid < 8) wsum[tid] = s;
    }
    __syncthreads();
    int excl = ((w > 0) ? wsum[w - 1] : 0) + sv - hv;
    lexcl[tid] = excl;
    lcur[tid] = excl;
    // reserve global chunk per bucket (one atomic per non-empty bucket)
    if (tid < FB && hv > 0) lbase[tid] = atomicAdd(&cur[tid], hv);
    __syncthreads();
    // pass B: place packed values into LDS at sorted positions
    #pragma unroll 8
    for (int it = 0; it < T_TILE / 512; ++it) {
        int e = base + it * 512 + tid;
        if (e < E) {
            unsigned d = (unsigned)dst[e];
            unsigned s = (unsigned)src[e];
            int pos = atomicAdd(&lcur[d >> FBB], 1);
            lpk[pos] = (d & 1023u) | (s << FBB);
        }
    }
    __syncthreads();
    // flush: wave-parallel per-bucket contiguous copy (R21-proven)
    for (int fb = w; fb < FB; fb += 8) {
        int cntb = lhist[fb];
        if (cntb == 0) continue;
        int lo = lexcl[fb], gb = lbase[fb];
        for (int t2 = lane; t2 < cntb; t2 += 64)
            pk1[gb + t2] = lpk[lo + t2];
    }
}

// ---- compact csr bases from final cursors (single block) ----
__global__ void bases_fix(const int* __restrict__ cur, int* __restrict__ csrbase,
                          int* __restrict__ rowptr, int FB, int N, int E) {
    __shared__ int lds[FB_MAX];
    int t = threadIdx.x;
    int c = (t < FB) ? (cur[t] - t * CAP_F) : 0;
    lds[t] = c;
    __syncthreads();
    for (int off = 1; off < FB_MAX; off <<= 1) {
        int a = (t >= off) ? lds[t - off] : 0;
        __syncthreads();
        lds[t] += a;
        __syncthreads();
    }
    if (t < FB) csrbase[t] = lds[t] - c;  // exclusive
    if (t == 0) { csrbase[FB] = E; rowptr[N] = E; }
}

// ---- pass 2: per-fine-bucket node sort -> csr + rowptr + dinv + z1 ----
__global__ void __launch_bounds__(1024)
buildfine(const unsigned* __restrict__ pk1, const int* __restrict__ csrbase,
          const float* __restrict__ x, int* __restrict__ rowptr,
          float* __restrict__ dinv, unsigned* __restrict__ z1h,
          unsigned* __restrict__ csr, int N) {
    __shared__ int cnt[1024];
    __shared__ int cur[1024];
    __shared__ unsigned eb[EB_CAP];
    __shared__ int wsum[16];
    int fb = blockIdx.x, tid = threadIdx.x;
    int lane = tid & 63, w = tid >> 6;
    int cb = csrbase[fb];
    int n = csrbase[fb + 1] - cb;
    size_t pbase = (size_t)fb * CAP_F;
    cnt[tid] = 0;
    __syncthreads();
    // pass A: per-node degree
    int k0 = 0;
    for (; k0 + 8192 <= n; k0 += 8192) {
        unsigned p[8];
        #pragma unroll
        for (int u = 0; u < 8; ++u) p[u] = pk1[pbase + k0 + tid + u * 1024];
        #pragma unroll
        for (int u = 0; u < 8; ++u) atomicAdd(&cnt[p[u] & 1023u], 1);
    }
    for (int k = k0 + tid; k < n; k += 1024)
        atomicAdd(&cnt[pk1[pbase + k] & 1023u], 1);
    __syncthreads();
    // wave-shuffle exclusive scan over 1024 node counts
    int c = cnt[tid];
    int sv = c;
    #pragma unroll
    for (int d = 1; d < 64; d <<= 1) {
        int sy = __shfl_up(sv, d, 64);
        if (lane >= d) sv += sy;
    }
    if (lane == 63) wsum[w] = sv;
    __syncthreads();
    if (tid < 64) {
        int s = (tid < 16) ? wsum[tid] : 0;
        #pragma unroll
        for (int d = 1; d < 16; d <<= 1) {
            int sy = __shfl_up(s, d, 64);
            if (tid >= d) s += sy;
        }
        if (tid < 16) wsum[tid] = s;
    }
    __syncthreads();
    int excl = ((w > 0) ? wsum[w - 1] : 0) + sv - c;
    int i = (fb << FBB) + tid;
    if (i < N) {
        rowptr[i] = cb + excl;
        float di = rsqrtf((float)c + 1.0f);
        dinv[i] = di;
        float2 xv = ((const float2*)x)[i];
        __half2 hz = __floats2half2_rn(xv.x * di, xv.y * di);
        z1h[i] = *(unsigned*)&hz;
    }
    cur[tid] = excl;
    __syncthreads();
    // pass B: place srcs sorted by node (bucket region is L2-warm)
    if (n <= EB_CAP) {
        k0 = 0;
        for (; k0 + 8192 <= n; k0 += 8192) {
            unsigned p[8];
            #pragma unroll
            for (int u = 0; u < 8; ++u) p[u] = pk1[pbase + k0 + tid + u * 1024];
            #pragma unroll
            for (int u = 0; u < 8; ++u) {
                int pos = atomicAdd(&cur[p[u] & 1023u], 1);
                eb[pos] = p[u] >> FBB;
            }
        }
        for (int k = k0 + tid; k < n; k += 1024) {
            unsigned p = pk1[pbase + k];
            int pos = atomicAdd(&cur[p & 1023u], 1);
            eb[pos] = p >> FBB;
        }
        __syncthreads();
        for (int k = tid; k < n; k += 1024) csr[cb + k] = eb[k];
    } else {
        for (int k = tid; k < n; k += 1024) {
            unsigned p = pk1[pbase + k];
            int pos = atomicAdd(&cur[p & 1023u], 1);
            csr[cb + pos] = p >> FBB;
        }
    }
}

// ---------------- GCN layers (R21-proven pull mode) ----------------

__global__ void gcn1(const int* __restrict__ rowptr, const unsigned* __restrict__ csr,
                     const unsigned* __restrict__ z1h, const float* __restrict__ W1,
                     const float* __restrict__ b1, const float* __restrict__ dinv,
                     uint2* __restrict__ z2h, int N) {
    int i = blockIdx.x * blockDim.x + threadIdx.x;
    if (i >= N) return;
    int r0 = rowptr[i], r1 = rowptr[i + 1];
    float a0, a1;
    {
        unsigned zr = z1h[i];
        float2 zi = __half22float2(*(__half2*)&zr);
        a0 = zi.x; a1 = zi.y;
    }
    int k = r0;
    for (; k + 16 <= r1; k += 16) {
        unsigned j[16];
        #pragma unroll
        for (int u = 0; u < 16; ++u) j[u] = __builtin_nontemporal_load(&csr[k + u]);
        unsigned raw[16];
        #pragma unroll
        for (int u = 0; u < 16; ++u) raw[u] = z1h[j[u]];
        #pragma unroll
        for (int u = 0; u < 16; ++u) {
            float2 v = __half22float2(*(__half2*)&raw[u]);
            a0 += v.x; a1 += v.y;
        }
    }
    for (; k < r1; ++k) {
        unsigned zr = z1h[csr[k]];
        float2 zv = __half22float2(*(__half2*)&zr);
        a0 += zv.x; a1 += zv.y;
    }
    float di = dinv[i];
    float g0 = di * a0, g1 = di * a1;
    float o0 = di * tanhf(fmaf(g0, W1[0], fmaf(g1, W1[4], b1[0])));
    float o1 = di * tanhf(fmaf(g0, W1[1], fmaf(g1, W1[5], b1[1])));
    float o2 = di * tanhf(fmaf(g0, W1[2], fmaf(g1, W1[6], b1[2])));
    float o3 = di * tanhf(fmaf(g0, W1[3], fmaf(g1, W1[7], b1[3])));
    __half2 ha = __floats2half2_rn(o0, o1);
    __half2 hb = __floats2half2_rn(o2, o3);
    uint2 packed;
    packed.x = *(unsigned*)&ha;
    packed.y = *(unsigned*)&hb;
    z2h[i] = packed;
}

__global__ void gcn2(const int* __restrict__ rowptr, const unsigned* __restrict__ csr,
                     const uint2* __restrict__ z2h, const float* __restrict__ W2,
                     const float* __restrict__ b2, const float* __restrict__ W3,
                     const float* __restrict__ dinv, unsigned* __restrict__ z3h, int N) {
    int i = blockIdx.x * blockDim.x + threadIdx.x;
    if (i >= N) return;
    int r0 = rowptr[i], r1 = rowptr[i + 1];
    float a0, a1, a2, a3;
    {
        uint2 raw = z2h[i];
        float2 f01 = __half22float2(*(__half2*)&raw.x);
        float2 f23 = __half22float2(*(__half2*)&raw.y);
        a0 = f01.x; a1 = f01.y; a2 = f23.x; a3 = f23.y;
    }
    int k = r0;
    for (; k + 8 <= r1; k += 8) {
        unsigned j[8];
        #pragma unroll
        for (int u = 0; u < 8; ++u) j[u] = __builtin_nontemporal_load(&csr[k + u]);
        uint2 raw[8];
        #pragma unroll
        for (int u = 0; u < 8; ++u) raw[u] = z2h[j[u]];
        #pragma unroll
        for (int u = 0; u < 8; ++u) {
            float2 f01 = __half22float2(*(__half2*)&raw[u].x);
            float2 f23 = __half22float2(*(__half2*)&raw[u].y);
            a0 += f01.x; a1 += f01.y; a2 += f23.x; a3 += f23.y;
        }
    }
    for (; k < r1; ++k) {
        uint2 raw = z2h[csr[k]];
        float2 f01 = __half22float2(*(__half2*)&raw.x);
        float2 f23 = __half22float2(*(__half2*)&raw.y);
        a0 += f01.x; a1 += f01.y; a2 += f23.x; a3 += f23.y;
    }
    float di = dinv[i];
    float g0 = di * a0, g1 = di * a1, g2 = di * a2, g3 = di * a3;
    float h[4];
    #pragma unroll
    for (int c = 0; c < 4; ++c)
        h[c] = tanhf(b2[c] + g0 * W2[c] + g1 * W2[4 + c] + g2 * W2[8 + c] + g3 * W2[12 + c]);
    float v0 = h[0] * W3[0] + h[1] * W3[2] + h[2] * W3[4] + h[3] * W3[6];
    float v1 = h[0] * W3[1] + h[1] * W3[3] + h[2] * W3[5] + h[3] * W3[7];
    __half2 hz = __floats2half2_rn(v0 * di, v1 * di);
    z3h[i] = *(unsigned*)&hz;
}

__global__ void gcn3(const int* __restrict__ rowptr, const unsigned* __restrict__ csr,
                     const unsigned* __restrict__ z3h, const float* __restrict__ b3,
                     const float* __restrict__ dinv, float* __restrict__ out, int N) {
    int i = blockIdx.x * blockDim.x + threadIdx.x;
    if (i >= N) return;
    int r0 = rowptr[i], r1 = rowptr[i + 1];
    float a0, a1;
    {
        unsigned zr = z3h[i];
        float2 zi = __half22float2(*(__half2*)&zr);
        a0 = zi.x; a1 = zi.y;
    }
    int k = r0;
    for (; k + 16 <= r1; k += 16) {
        unsigned j[16];
        #pragma unroll
        for (int u = 0; u < 16; ++u) j[u] = __builtin_nontemporal_load(&csr[k + u]);
        unsigned raw[16];
        #pragma unroll
        for (int u = 0; u < 16; ++u) raw[u] = z3h[j[u]];
        #pragma unroll
        for (int u = 0; u < 16; ++u) {
            float2 v = __half22float2(*(__half2*)&raw[u]);
            a0 += v.x; a1 += v.y;
        }
    }
    for (; k < r1; ++k) {
        unsigned zr = z3h[csr[k]];
        float2 zv = __half22float2(*(__half2*)&zr);
        a0 += zv.x; a1 += zv.y;
    }
    float di = dinv[i];
    ((float2*)out)[i] = make_float2(fmaf(di, a0, b3[0]), fmaf(di, a1, b3[1]));
}

extern "C" void kernel_launch(void* const* d_in, const int* in_sizes, int n_in,
                              void* d_out, int out_size, void* d_ws, size_t ws_size,
                              hipStream_t stream) {
    const float* x  = (const float*)d_in[0];
    const int*   ei = (const int*)d_in[1];
    const float* W1 = (const float*)d_in[2];
    const float* b1 = (const float*)d_in[3];
    const float* W2 = (const float*)d_in[4];
    const float* b2 = (const float*)d_in[5];
    const float* W3 = (const float*)d_in[6];
    const float* b3 = (const float*)d_in[7];
    float* out = (float*)d_out;

    const int N = in_sizes[0] / 2;
    const int E = in_sizes[1] / 2;
    const int* src = ei;
    const int* dst = ei + E;

    const int FB  = (N + (1 << FBB) - 1) >> FBB;     // 489 fine buckets
    const int ntB = (E + T_TILE - 1) / T_TILE;       // 977 tiles of 16K edges

    // ws layout (256B-aligned)
    auto align = [](size_t o) { return (o + 255) & ~(size_t)255; };
    char* wbase = (char*)d_ws;
    size_t off = 0;
    float*    dinv    = (float*)(wbase + off);    off = align(off + (size_t)N * 4);
    unsigned* z1h     = (unsigned*)(wbase + off); off = align(off + (size_t)N * 4);
    uint2*    z2h     = (uint2*)(wbase + off);    off = align(off + (size_t)N * 8);
    unsigned* z3h     = (unsigned*)(wbase + off); off = align(off + (size_t)N * 4);
    int*      rowptr  = (int*)(wbase + off);      off = align(off + (size_t)(N + 1) * 4);
    int*      cur     = (int*)(wbase + off);      off = align(off + (size_t)FB_MAX * 4);
    int*      csrbase = (int*)(wbase + off);      off = align(off + (size_t)(FB_MAX + 1) * 4);
    unsigned* pk1     = (unsigned*)(wbase + off); off = align(off + (size_t)FB * CAP_F * 4);
    unsigned* csr     = (unsigned*)(wbase + off); off = align(off + (size_t)E * 4);

    dim3 gN((N + TPB - 1) / TPB);
    initcur<<<dim3(1), dim3(512), 0, stream>>>(cur, FB);
    scatter1<<<dim3(ntB), dim3(512), 0, stream>>>(dst, src, cur, pk1, E, FB);
    bases_fix<<<dim3(1), dim3(512), 0, stream>>>(cur, csrbase, rowptr, FB, N, E);
    buildfine<<<dim3(FB), dim3(1024), 0, stream>>>(pk1, csrbase, x, rowptr, dinv,
                                                   z1h, csr, N);
    gcn1<<<gN, dim3(TPB), 0, stream>>>(rowptr, csr, z1h, W1, b1, dinv, z2h, N);
    gcn2<<<gN, dim3(TPB), 0, stream>>>(rowptr, csr, z2h, W2, b2, W3, dinv, z3h, N);
    gcn3<<<gN, dim3(TPB), 0, stream>>>(rowptr, csr, z3h, b3, dinv, out, N);
}